// Round 20
// baseline (303.760 us; speedup 1.0000x reference)
//
#include <hip/hip_runtime.h>

#define VOCAB 21
#define EMB 128
#define H1 64
#define H2 100
#define T1 500
#define TP 100
#define NB 1024
#define TBL_LD 260
#define LOG2E 1.44269504f

typedef __attribute__((ext_vector_type(8))) short bf16x8;
typedef __attribute__((ext_vector_type(4))) float f32x4;

__device__ __forceinline__ unsigned short f2bf(float x){
    union { float f; unsigned u; } v; v.f = x;
    return (unsigned short)((v.u + 0x8000u) >> 16);
}
// LDS-only barrier: do NOT drain vmcnt (global stores/loads stay in flight)
__device__ __forceinline__ void bar_lds(){
    asm volatile("s_waitcnt lgkmcnt(0)\n\ts_barrier" ::: "memory");
}
__device__ __forceinline__ float ex2(float x){ return __builtin_amdgcn_exp2f(x); }
__device__ __forceinline__ float rcp(float x){ return __builtin_amdgcn_rcpf(x); }

// ---------------------------------------------------------------------------
// Kernel 0: permuted xproj table, pre-scaled by log2(e). [v][p], stride 260.
// ---------------------------------------------------------------------------
__global__ void k_table(const float* __restrict__ Wih, const float* __restrict__ emb,
                        const float* __restrict__ bih, const float* __restrict__ bhh,
                        float* __restrict__ table){
    const int p = threadIdx.x;
    const int v = blockIdx.x;
    const int orig = (p & 3) * H1 + (p >> 2);
    float s = bih[orig] + bhh[orig];
    if (v != 0){
        const float* w = Wih + orig * EMB;
        const float* e = emb + v * EMB;
        #pragma unroll 16
        for (int d = 0; d < EMB; ++d) s += w[d]*e[d];
    }
    table[v*TBL_LD + p] = s * LOG2E;
}

// ---------------------------------------------------------------------------
// Fused kernel (R17 structure + split-acc lstm1 + 25-tile lstm2).
// 64 blocks x 1024 threads (16 waves). lstm1: 1 tile/wave, zero junk/
// redistribute, split accumulators. Every 5th step -> LDS pool; then ONE
// inline lstm2 chunk (25 tiles: waves 0-8 x2, waves 9-15 x1, producer-
// direct, h2 in LDS ping-pong). No global x2, no 2nd kernel.
// ---------------------------------------------------------------------------
__global__ __launch_bounds__(1024, 1) void k_fused(
    const int* __restrict__ xidx, const float* __restrict__ Whh1,
    const float* __restrict__ tbl_g,
    const float* __restrict__ Wih2, const float* __restrict__ Whh2,
    const float* __restrict__ bih2, const float* __restrict__ bhh2,
    const float* __restrict__ fcw, const float* __restrict__ fcb,
    float* __restrict__ out){
  __shared__ __align__(16) float table[VOCAB*TBL_LD];       // 21840 B
  __shared__ __align__(16) unsigned short hbuf[2][16*64];   // 4096 B
  __shared__ __align__(16) unsigned short pool[2][16*64];   // 4096 B
  __shared__ __align__(16) unsigned short h2buf[2][16*128]; // 8192 B
  __shared__ int idxs[16*T1];                               // 32000 B
  __shared__ float fcred[16][16];                           // 1024 B

  const int tid = threadIdx.x;
  const int gt = tid >> 6, l = tid & 63;     // wave index / lane
  const int b0 = blockIdx.x * 16;
  const int row = l & 15, kg = l >> 4;       // batch row (MFMA col) / k-group

  for (int i = tid; i < VOCAB*TBL_LD; i += 1024) table[i] = tbl_g[i];
  for (int i = tid; i < 16*T1; i += 1024){
      int r = i / T1, t = i - r*T1;
      idxs[i] = xidx[(b0 + r)*T1 + t];
  }
  { unsigned short* hz = (unsigned short*)hbuf;
    for (int i = tid; i < 2048; i += 1024) hz[i] = 0; }
  { unsigned short* hz = (unsigned short*)h2buf;
    for (int i = tid; i < 4096; i += 1024) hz[i] = 0; }

  // ---- lstm1 A-fragments (tile gt), * LOG2E ----
  bf16x8 af0, af1;
  {
      const int p = 16*gt + row;
      const int orig = (p & 3)*H1 + (p >> 2);
      bf16x8 f;
      const float* s0 = Whh1 + orig*H1 + kg*8;
      #pragma unroll
      for (int j = 0; j < 8; ++j) f[j] = (short)f2bf(s0[j] * LOG2E);
      af0 = f;
      const float* s1 = Whh1 + orig*H1 + 32 + kg*8;
      #pragma unroll
      for (int j = 0; j < 8; ++j) f[j] = (short)f2bf(s1[j] * LOG2E);
      af1 = f;
  }

  // ---- lstm2 tile assignment: 25 real tiles (4*H2=400 gates exactly).
  // waves 0-8 -> 2 tiles (0..17), waves 9-15 -> 1 tile (18..24).
  const int nt2  = (gt < 9) ? 2 : 1;
  const int t2lo = (gt < 9) ? 2*gt : gt + 9;

  // lstm2 A-fragments [u][c], K = [x(64) | h2(100 pad 128)], * LOG2E
  bf16x8 af2[2][6];
  #pragma unroll
  for (int u = 0; u < 2; ++u){
      if (u < nt2){
          const int p = 16*(t2lo + u) + row;
          const int cell_ = p >> 2, gate = p & 3;
          #pragma unroll
          for (int c = 0; c < 6; ++c){
              bf16x8 f;
              #pragma unroll
              for (int jj = 0; jj < 8; ++jj){
                  int k = c*32 + kg*8 + jj;
                  float vv = 0.f;
                  if (cell_ < H2){
                      if (k < 64)           vv = Wih2[(gate*H2 + cell_)*H1 + k];
                      else if (k < 64 + H2) vv = Whh2[(gate*H2 + cell_)*H2 + (k - 64)];
                  }
                  f[jj] = (short)f2bf(vv * LOG2E);
              }
              af2[u][c] = f;
          }
      }
  }

  // lstm2 per-lane constants (producer-direct: cell = 4*(t2lo+u)+kg, row)
  f32x4 bz2[2];
  int cu2[2], wbh2[2];
  float fw2[2];
  const int swz = (row & 7) << 4;
  #pragma unroll
  for (int u = 0; u < 2; ++u){
      cu2[u] = 4*(t2lo + u) + kg;
      f32x4 b = {0.f,0.f,0.f,0.f};
      float fv = 0.f;
      if (u < nt2 && cu2[u] < H2){
          #pragma unroll
          for (int g = 0; g < 4; ++g)
              b[g] = (bih2[g*H2 + cu2[u]] + bhh2[g*H2 + cu2[u]]) * LOG2E;
          fv = fcw[cu2[u]];
      }
      bz2[u] = b; fw2[u] = fv;
      wbh2[u] = (row*256 + 2*cu2[u]) ^ swz;
  }
  const float twoL = 2.0f * LOG2E;

  // ---- addresses ----
  char* hb  = (char*)hbuf;
  char* pb  = (char*)pool;
  char* h2b = (char*)h2buf;
  const int rb0  = (row*128 + 16*kg) ^ swz;       // hbuf/pool chunk 0
  const int rb1  = (row*128 + 64 + 16*kg) ^ swz;  // chunk 1
  const int cell1 = 4*gt + kg;
  const int wbh1 = (row*128 + 2*cell1) ^ swz;     // hbuf & pool write
  int rbh2[4];
  #pragma unroll
  for (int j = 0; j < 4; ++j)
      rbh2[j] = (row*256 + 2*(j*32 + 8*kg)) ^ swz;

  float cc1 = 0.f, pm = -1e30f;
  float cc2[2] = {0.f, 0.f}, hv2[2] = {0.f, 0.f};
  __syncthreads();

  int vv = idxs[row*T1];
  f32x4 tq = *(const f32x4*)&table[vv*TBL_LD + 4*cell1];
  int vnext = idxs[row*T1 + 1];
  const f32x4 z4 = {0.f, 0.f, 0.f, 0.f};

  int rp1 = 0, rp2 = 0, t = 0;
  for (int tp = 0; tp < TP; ++tp){
      #pragma unroll
      for (int s = 0; s < 5; ++s, ++t){
          // ---------- lstm1 step t (split accumulators) ----------
          bf16x8 bf0 = *(const bf16x8*)(hb + rp1 + rb0);
          bf16x8 bf1 = *(const bf16x8*)(hb + rp1 + rb1);
          f32x4 a = __builtin_amdgcn_mfma_f32_16x16x32_bf16(af0, bf0, tq, 0,0,0);
          f32x4 b = __builtin_amdgcn_mfma_f32_16x16x32_bf16(af1, bf1, z4, 0,0,0);
          f32x4 z = a + b;
          f32x4 tqn = *(const f32x4*)&table[vnext*TBL_LD + 4*cell1];
          int vn2 = idxs[row*T1 + ((t + 2 < T1) ? (t + 2) : 0)];
          float si = rcp(1.f + ex2(-z[0]));
          float sf = rcp(1.f + ex2(-z[1]));
          float so = rcp(1.f + ex2(-z[3]));
          float tg = 1.f - 2.f*rcp(1.f + ex2(z[2] + z[2]));
          cc1 = sf*cc1 + si*tg;
          float th = 1.f - 2.f*rcp(1.f + ex2(twoL*cc1));
          float h = so*th;
          const int wp1 = rp1 ^ 2048;
          *(unsigned short*)(hb + wp1 + wbh1) = f2bf(h);
          pm = fmaxf(pm, h);
          if (s == 4){
              *(unsigned short*)(pb + ((tp & 1) ? 2048 : 0) + wbh1) = f2bf(pm);
              pm = -1e30f;
          }
          tq = tqn; vnext = vn2;
          rp1 = wp1;
          bar_lds();
      }
      // ---------- lstm2 step tp (inline chunk) ----------
      {
          const int po = (tp & 1) ? 2048 : 0;
          bf16x8 x0 = *(const bf16x8*)(pb + po + rb0);
          bf16x8 x1 = *(const bf16x8*)(pb + po + rb1);
          bf16x8 h20 = *(const bf16x8*)(h2b + rp2 + rbh2[0]);
          bf16x8 h21 = *(const bf16x8*)(h2b + rp2 + rbh2[1]);
          bf16x8 h22 = *(const bf16x8*)(h2b + rp2 + rbh2[2]);
          bf16x8 h23 = *(const bf16x8*)(h2b + rp2 + rbh2[3]);
          const int wp2 = rp2 ^ 4096;
          #pragma unroll
          for (int u = 0; u < 2; ++u){
              if (u < nt2){
                  f32x4 za = __builtin_amdgcn_mfma_f32_16x16x32_bf16(af2[u][0], x0, bz2[u], 0,0,0);
                  f32x4 zb = __builtin_amdgcn_mfma_f32_16x16x32_bf16(af2[u][1], x1, z4, 0,0,0);
                  za = __builtin_amdgcn_mfma_f32_16x16x32_bf16(af2[u][2], h20, za, 0,0,0);
                  zb = __builtin_amdgcn_mfma_f32_16x16x32_bf16(af2[u][3], h21, zb, 0,0,0);
                  za = __builtin_amdgcn_mfma_f32_16x16x32_bf16(af2[u][4], h22, za, 0,0,0);
                  zb = __builtin_amdgcn_mfma_f32_16x16x32_bf16(af2[u][5], h23, zb, 0,0,0);
                  f32x4 q = za + zb;
                  float si = rcp(1.f + ex2(-q[0]));
                  float sf = rcp(1.f + ex2(-q[1]));
                  float so = rcp(1.f + ex2(-q[3]));
                  float tg = 1.f - 2.f*rcp(1.f + ex2(q[2] + q[2]));
                  cc2[u] = sf*cc2[u] + si*tg;
                  float th = 1.f - 2.f*rcp(1.f + ex2(twoL*cc2[u]));
                  hv2[u] = so*th;
                  if (cu2[u] < H2)
                      *(unsigned short*)(h2b + wp2 + wbh2[u]) = f2bf(hv2[u]);
              }
          }
          rp2 = wp2;
          // no extra barrier: next window's first bar_lds orders these LDS ops
      }
  }

  // ---------- FC + sigmoid ----------
  float p = 0.f;
  #pragma unroll
  for (int u = 0; u < 2; ++u)
      if (u < nt2 && cu2[u] < H2) p += hv2[u] * fw2[u];
  p += __shfl_xor(p, 16);
  p += __shfl_xor(p, 32);
  if (l < 16) fcred[gt][l] = p;
  __syncthreads();
  if (tid < 16){
      float s = 0.f;
      #pragma unroll
      for (int ww = 0; ww < 16; ++ww) s += fcred[ww][tid];
      s += fcb[0];
      out[b0 + tid] = rcp(1.f + ex2(-s * LOG2E));
  }
}

// ---------------------------------------------------------------------------
extern "C" void kernel_launch(void* const* d_in, const int* in_sizes, int n_in,
                              void* d_out, int out_size, void* d_ws, size_t ws_size,
                              hipStream_t stream) {
    const int*   x_idx = (const int*)  d_in[0];
    const float* emb   = (const float*)d_in[1];
    const float* Wih1  = (const float*)d_in[2];
    const float* Whh1  = (const float*)d_in[3];
    const float* bih1  = (const float*)d_in[4];
    const float* bhh1  = (const float*)d_in[5];
    const float* Wih2  = (const float*)d_in[6];
    const float* Whh2  = (const float*)d_in[7];
    const float* bih2  = (const float*)d_in[8];
    const float* bhh2  = (const float*)d_in[9];
    const float* fcw   = (const float*)d_in[10];
    const float* fcb   = (const float*)d_in[11];
    float* out = (float*)d_out;

    float* table = (float*)d_ws;                       // 21840 B

    k_table<<<VOCAB, 256, 0, stream>>>(Wih1, emb, bih1, bhh1, table);
    k_fused<<<NB / 16, 1024, 0, stream>>>(x_idx, Whh1, table,
                                          Wih2, Whh2, bih2, bhh2,
                                          fcw, fcb, out);
}

// Round 21
// 289.241 us; speedup vs baseline: 1.0502x; 1.0502x over previous
//
#include <hip/hip_runtime.h>

#define VOCAB 21
#define EMB 128
#define H1 64
#define H2 100
#define T1 500
#define TP 100
#define NB 1024
#define TBL_LD 260
#define LOG2E 1.44269504f

typedef __attribute__((ext_vector_type(8))) short bf16x8;
typedef __attribute__((ext_vector_type(4))) float f32x4;

__device__ __forceinline__ unsigned short f2bf(float x){
    union { float f; unsigned u; } v; v.f = x;
    return (unsigned short)((v.u + 0x8000u) >> 16);
}
// LDS-only barrier: do NOT drain vmcnt (global stores/loads stay in flight)
__device__ __forceinline__ void bar_lds(){
    asm volatile("s_waitcnt lgkmcnt(0)\n\ts_barrier" ::: "memory");
}
__device__ __forceinline__ float ex2(float x){ return __builtin_amdgcn_exp2f(x); }
__device__ __forceinline__ float rcp(float x){ return __builtin_amdgcn_rcpf(x); }

// ---------------------------------------------------------------------------
// Kernel 0: permuted xproj table, pre-scaled by log2(e). [v][p], stride 260.
// ---------------------------------------------------------------------------
__global__ void k_table(const float* __restrict__ Wih, const float* __restrict__ emb,
                        const float* __restrict__ bih, const float* __restrict__ bhh,
                        float* __restrict__ table){
    const int p = threadIdx.x;
    const int v = blockIdx.x;
    const int orig = (p & 3) * H1 + (p >> 2);
    float s = bih[orig] + bhh[orig];
    if (v != 0){
        const float* w = Wih + orig * EMB;
        const float* e = emb + v * EMB;
        #pragma unroll 16
        for (int d = 0; d < EMB; ++d) s += w[d]*e[d];
    }
    table[v*TBL_LD + p] = s * LOG2E;
}

// ---------------------------------------------------------------------------
// Fused kernel: both LSTMs + pool + FC for 16 batch rows per block.
// 64 blocks x 1024 threads (16 waves). lstm1 = R12 structure (1 tile/wave,
// zero junk/redistribute). Every 5th step writes the pooled vector to an LDS
// ping-pong pool; then ONE inline lstm2 step (26 tiles split 2x10+1x6 over
// waves, producer-direct, h2 in LDS ping-pong). No global x2, no 2nd kernel.
// Sync audit: pool/h2 ping-pong + each wave's bar_lds (lgkm drain) orders all
// cross-wave reads before the conflicting write 5 barriers later.
// ---------------------------------------------------------------------------
__global__ __launch_bounds__(1024, 1) void k_fused(
    const int* __restrict__ xidx, const float* __restrict__ Whh1,
    const float* __restrict__ tbl_g,
    const float* __restrict__ Wih2, const float* __restrict__ Whh2,
    const float* __restrict__ bih2, const float* __restrict__ bhh2,
    const float* __restrict__ fcw, const float* __restrict__ fcb,
    float* __restrict__ out){
  __shared__ __align__(16) float table[VOCAB*TBL_LD];       // 21840 B
  __shared__ __align__(16) unsigned short hbuf[2][16*64];   // 4096 B
  __shared__ __align__(16) unsigned short pool[2][16*64];   // 4096 B
  __shared__ __align__(16) unsigned short h2buf[2][16*128]; // 8192 B
  __shared__ int idxs[16*T1];                               // 32000 B
  __shared__ float fcred[16][16];                           // 1024 B

  const int tid = threadIdx.x;
  const int gt = tid >> 6, l = tid & 63;     // wave index / lane
  const int b0 = blockIdx.x * 16;
  const int row = l & 15, kg = l >> 4;       // batch row (MFMA col) / k-group

  for (int i = tid; i < VOCAB*TBL_LD; i += 1024) table[i] = tbl_g[i];
  for (int i = tid; i < 16*T1; i += 1024){
      int r = i / T1, t = i - r*T1;
      idxs[i] = xidx[(b0 + r)*T1 + t];
  }
  { unsigned short* hz = (unsigned short*)hbuf;
    for (int i = tid; i < 2048; i += 1024) hz[i] = 0; }
  { unsigned short* hz = (unsigned short*)h2buf;
    for (int i = tid; i < 4096; i += 1024) hz[i] = 0; }

  // ---- lstm1 A-fragments (tile gt), * LOG2E ----
  bf16x8 af0, af1;
  {
      const int p = 16*gt + row;
      const int orig = (p & 3)*H1 + (p >> 2);
      bf16x8 f;
      const float* s0 = Whh1 + orig*H1 + kg*8;
      #pragma unroll
      for (int j = 0; j < 8; ++j) f[j] = (short)f2bf(s0[j] * LOG2E);
      af0 = f;
      const float* s1 = Whh1 + orig*H1 + 32 + kg*8;
      #pragma unroll
      for (int j = 0; j < 8; ++j) f[j] = (short)f2bf(s1[j] * LOG2E);
      af1 = f;
  }

  // ---- lstm2 tile assignment: waves 0-9 -> 2 tiles, waves 10-15 -> 1 ----
  const int nt2  = (gt < 10) ? 2 : 1;
  const int t2lo = (gt < 10) ? 2*gt : gt + 10;

  // lstm2 A-fragments [u][c], K = [x(64) | h2(100 pad 128)], * LOG2E
  bf16x8 af2[2][6];
  #pragma unroll
  for (int u = 0; u < 2; ++u){
      if (u < nt2){
          const int p = 16*(t2lo + u) + row;
          const int cell_ = p >> 2, gate = p & 3;
          #pragma unroll
          for (int c = 0; c < 6; ++c){
              bf16x8 f;
              #pragma unroll
              for (int jj = 0; jj < 8; ++jj){
                  int k = c*32 + kg*8 + jj;
                  float vv = 0.f;
                  if (cell_ < H2){
                      if (k < 64)           vv = Wih2[(gate*H2 + cell_)*H1 + k];
                      else if (k < 64 + H2) vv = Whh2[(gate*H2 + cell_)*H2 + (k - 64)];
                  }
                  f[jj] = (short)f2bf(vv * LOG2E);
              }
              af2[u][c] = f;
          }
      }
  }

  // lstm2 per-lane constants (producer-direct: cell = 4*(t2lo+u)+kg, row)
  f32x4 bz2[2];
  int cu2[2], wbh2[2];
  float fw2[2];
  const int swz = (row & 7) << 4;
  #pragma unroll
  for (int u = 0; u < 2; ++u){
      cu2[u] = 4*(t2lo + u) + kg;
      f32x4 b = {0.f,0.f,0.f,0.f};
      float fv = 0.f;
      if (u < nt2 && cu2[u] < H2){
          #pragma unroll
          for (int g = 0; g < 4; ++g)
              b[g] = (bih2[g*H2 + cu2[u]] + bhh2[g*H2 + cu2[u]]) * LOG2E;
          fv = fcw[cu2[u]];
      }
      bz2[u] = b; fw2[u] = fv;
      wbh2[u] = (row*256 + 2*cu2[u]) ^ swz;
  }
  const float twoL = 2.0f * LOG2E;

  // ---- addresses ----
  char* hb  = (char*)hbuf;
  char* pb  = (char*)pool;
  char* h2b = (char*)h2buf;
  const int rb0  = (row*128 + 16*kg) ^ swz;       // hbuf/pool chunk 0
  const int rb1  = (row*128 + 64 + 16*kg) ^ swz;  // chunk 1
  const int cell1 = 4*gt + kg;
  const int wbh1 = (row*128 + 2*cell1) ^ swz;     // hbuf & pool write
  int rbh2[4];
  #pragma unroll
  for (int j = 0; j < 4; ++j)
      rbh2[j] = (row*256 + 2*(j*32 + 8*kg)) ^ swz;

  float cc1 = 0.f, pm = -1e30f;
  float cc2[2] = {0.f, 0.f}, hv2[2] = {0.f, 0.f};
  __syncthreads();

  int vv = idxs[row*T1];
  f32x4 tq = *(const f32x4*)&table[vv*TBL_LD + 4*cell1];
  int vnext = idxs[row*T1 + 1];

  int rp1 = 0, rp2 = 0, t = 0;
  for (int tp = 0; tp < TP; ++tp){
      #pragma unroll
      for (int s = 0; s < 5; ++s, ++t){
          // ---------- lstm1 step t ----------
          bf16x8 bf0 = *(const bf16x8*)(hb + rp1 + rb0);
          bf16x8 bf1 = *(const bf16x8*)(hb + rp1 + rb1);
          f32x4 a = __builtin_amdgcn_mfma_f32_16x16x32_bf16(af0, bf0, tq, 0,0,0);
          f32x4 z = __builtin_amdgcn_mfma_f32_16x16x32_bf16(af1, bf1, a, 0,0,0);
          f32x4 tqn = *(const f32x4*)&table[vnext*TBL_LD + 4*cell1];
          int vn2 = idxs[row*T1 + ((t + 2 < T1) ? (t + 2) : 0)];
          float si = rcp(1.f + ex2(-z[0]));
          float sf = rcp(1.f + ex2(-z[1]));
          float so = rcp(1.f + ex2(-z[3]));
          float tg = 1.f - 2.f*rcp(1.f + ex2(z[2] + z[2]));
          cc1 = sf*cc1 + si*tg;
          float th = 1.f - 2.f*rcp(1.f + ex2(twoL*cc1));
          float h = so*th;
          const int wp1 = rp1 ^ 2048;
          *(unsigned short*)(hb + wp1 + wbh1) = f2bf(h);
          pm = fmaxf(pm, h);
          if (s == 4){
              *(unsigned short*)(pb + ((tp & 1) ? 2048 : 0) + wbh1) = f2bf(pm);
              pm = -1e30f;
          }
          tq = tqn; vnext = vn2;
          rp1 = wp1;
          bar_lds();   // pool (s==4) is visible to all waves after this
      }
      // ---------- lstm2 step tp (inline) ----------
      {
          const int po = (tp & 1) ? 2048 : 0;
          bf16x8 x0 = *(const bf16x8*)(pb + po + rb0);
          bf16x8 x1 = *(const bf16x8*)(pb + po + rb1);
          bf16x8 h0 = *(const bf16x8*)(h2b + rp2 + rbh2[0]);
          bf16x8 h1 = *(const bf16x8*)(h2b + rp2 + rbh2[1]);
          bf16x8 h2 = *(const bf16x8*)(h2b + rp2 + rbh2[2]);
          bf16x8 h3 = *(const bf16x8*)(h2b + rp2 + rbh2[3]);
          const int wp2 = rp2 ^ 4096;
          #pragma unroll
          for (int u = 0; u < 2; ++u){
              if (u < nt2){
                  f32x4 za = __builtin_amdgcn_mfma_f32_16x16x32_bf16(af2[u][0], x0, bz2[u], 0,0,0);
                  f32x4 zb = __builtin_amdgcn_mfma_f32_16x16x32_bf16(af2[u][1], x1, (f32x4){0.f,0.f,0.f,0.f}, 0,0,0);
                  za = __builtin_amdgcn_mfma_f32_16x16x32_bf16(af2[u][2], h0, za, 0,0,0);
                  zb = __builtin_amdgcn_mfma_f32_16x16x32_bf16(af2[u][3], h1, zb, 0,0,0);
                  za = __builtin_amdgcn_mfma_f32_16x16x32_bf16(af2[u][4], h2, za, 0,0,0);
                  zb = __builtin_amdgcn_mfma_f32_16x16x32_bf16(af2[u][5], h3, zb, 0,0,0);
                  f32x4 q = za + zb;
                  float si = rcp(1.f + ex2(-q[0]));
                  float sf = rcp(1.f + ex2(-q[1]));
                  float so = rcp(1.f + ex2(-q[3]));
                  float tg = 1.f - 2.f*rcp(1.f + ex2(q[2] + q[2]));
                  cc2[u] = sf*cc2[u] + si*tg;
                  float th = 1.f - 2.f*rcp(1.f + ex2(twoL*cc2[u]));
                  hv2[u] = so*th;
                  if (cu2[u] < H2)
                      *(unsigned short*)(h2b + wp2 + wbh2[u]) = f2bf(hv2[u]);
              }
          }
          rp2 = wp2;
          // no extra barrier: next lstm1 step's bar_lds orders these LDS ops
      }
  }

  // ---------- FC + sigmoid ----------
  float p = 0.f;
  #pragma unroll
  for (int u = 0; u < 2; ++u)
      if (u < nt2 && cu2[u] < H2) p += hv2[u] * fw2[u];
  p += __shfl_xor(p, 16);
  p += __shfl_xor(p, 32);
  if (l < 16) fcred[gt][l] = p;
  __syncthreads();
  if (tid < 16){
      float s = 0.f;
      #pragma unroll
      for (int ww = 0; ww < 16; ++ww) s += fcred[ww][tid];
      s += fcb[0];
      out[b0 + tid] = rcp(1.f + ex2(-s * LOG2E));
  }
}

// ---------------------------------------------------------------------------
extern "C" void kernel_launch(void* const* d_in, const int* in_sizes, int n_in,
                              void* d_out, int out_size, void* d_ws, size_t ws_size,
                              hipStream_t stream) {
    const int*   x_idx = (const int*)  d_in[0];
    const float* emb   = (const float*)d_in[1];
    const float* Wih1  = (const float*)d_in[2];
    const float* Whh1  = (const float*)d_in[3];
    const float* bih1  = (const float*)d_in[4];
    const float* bhh1  = (const float*)d_in[5];
    const float* Wih2  = (const float*)d_in[6];
    const float* Whh2  = (const float*)d_in[7];
    const float* bih2  = (const float*)d_in[8];
    const float* bhh2  = (const float*)d_in[9];
    const float* fcw   = (const float*)d_in[10];
    const float* fcb   = (const float*)d_in[11];
    float* out = (float*)d_out;

    float* table = (float*)d_ws;                       // 21840 B

    k_table<<<VOCAB, 256, 0, stream>>>(Wih1, emb, bih1, bhh1, table);
    k_fused<<<NB / 16, 1024, 0, stream>>>(x_idx, Whh1, table,
                                          Wih2, Whh2, bih2, bhh2,
                                          fcw, fcb, out);
}